// Round 1
// baseline (491.955 us; speedup 1.0000x reference)
//
#include <hip/hip_runtime.h>
#include <math.h>

#pragma clang fp contract(off)

#define BS   32
#define A_N  8400
#define G_N  64
#define NC_N 80
#define TK   10

static __device__ __forceinline__ bool lexless(float v1, int i1, float v2, int i2) {
    return (v1 < v2) || (v1 == v2 && i1 < i2);
}

// ---------------------------------------------------------------------------
// Kernel 1: fused cls-cost + CIoU + gating  ->  cost[b][g][a]
// block = 64 threads (one wave), each thread owns one anchor 'a'
// grid  = (ceil(A/64), BS)
// ---------------------------------------------------------------------------
__global__ __launch_bounds__(64)
void k_cost(const float* __restrict__ pred_boxes,   // [BS][A][4]
            const float* __restrict__ gt_boxes,     // [BS][G][4]
            const float* __restrict__ pred_scores,  // [BS][A][NC]
            const int*   __restrict__ gt_labels,    // [BS][G]
            float* __restrict__ cost)               // [BS][G][A]
{
    __shared__ float s_delta[64 * 81];              // padded stride 81: conflict-free
    __shared__ float s_gx1[G_N], s_gy1[G_N], s_gx2[G_N], s_gy2[G_N];
    __shared__ float s_gsx[G_N], s_gsy[G_N];
    __shared__ float s_glx[G_N], s_gly[G_N], s_ghx[G_N], s_ghy[G_N];
    __shared__ float s_area2[G_N], s_atg[G_N];
    __shared__ int   s_lab[G_N];

    const float EPSF = 1e-9f;
    const int t = threadIdx.x;
    const int b = blockIdx.y;
    const int a = blockIdx.x * 64 + t;

    // --- per-gt preload: thread t handles gt g=t (block has exactly 64 threads)
    {
        const float4 gb = ((const float4*)gt_boxes)[b * G_N + t];
        const float gx1 = gb.x, gy1 = gb.y, gx2 = gb.z, gy2 = gb.w;
        s_gx1[t] = gx1; s_gy1[t] = gy1; s_gx2[t] = gx2; s_gy2[t] = gy2;
        const float sx = gx1 + gx2, sy = gy1 + gy2;
        s_gsx[t] = sx; s_gsy[t] = sy;
        const float cx = sx / 2.0f, cy = sy / 2.0f;        // matches (g1+g2)/2
        s_glx[t] = cx - 2.5f; s_ghx[t] = cx + 2.5f;
        s_gly[t] = cy - 2.5f; s_ghy[t] = cy + 2.5f;
        const float w2 = gx2 - gx1;
        const float h2 = (gy2 - gy1) + EPSF;
        s_area2[t] = w2 * h2;
        s_atg[t]   = atanf(w2 / h2);
        s_lab[t]   = gt_labels[b * G_N + t];
    }

    // --- per-anchor class terms: S and delta[c] into LDS
    float S = 0.0f;
    float4 pb = make_float4(0.f, 0.f, 0.f, 0.f);
    if (a < A_N) {
        const float* prow = pred_scores + ((size_t)b * A_N + a) * NC_N;
        const float LO = 1e-7f;
        const float HI = (float)(1.0 - 1e-7);
        for (int c = 0; c < NC_N; ++c) {
            float p = prow[c];
            p = fminf(fmaxf(p, LO), HI);
            const float l1mp = log1pf(-p);
            const float lp   = logf(p);
            S += l1mp;
            s_delta[t * 81 + c] = -(lp - l1mp);   // delta = -(logp - log1mp)
        }
        S = -S;                                   // S = -sum(log1mp)
        pb = ((const float4*)pred_boxes)[(size_t)b * A_N + a];
    }
    __syncthreads();
    if (a >= A_N) return;

    const float pcx  = (pb.x + pb.z) / 2.0f;
    const float pcy  = (pb.y + pb.w) / 2.0f;
    const float w1   = pb.z - pb.x;
    const float h1   = (pb.w - pb.y) + EPSF;
    const float area1 = w1 * h1;
    const float atp  = atanf(w1 / h1);
    const float KPI  = (float)(4.0 / (M_PI * M_PI));

    float* crow = cost + (size_t)b * G_N * A_N + a;
    for (int g = 0; g < G_N; ++g) {
        const float gx1 = s_gx1[g], gy1 = s_gy1[g], gx2 = s_gx2[g], gy2 = s_gy2[g];
        const bool inb  = (pcx > gx1) && (pcy > gy1) && (gx2 > pcx) && (gy2 > pcy);
        const bool inc  = (pcx > s_glx[g]) && (pcy > s_gly[g]) &&
                          (s_ghx[g] > pcx) && (s_ghy[g] > pcy);
        const bool both = inb && inc;

        const float iw    = fmaxf(fminf(pb.z, gx2) - fmaxf(pb.x, gx1), 0.0f);
        const float ih    = fmaxf(fminf(pb.w, gy2) - fmaxf(pb.y, gy1), 0.0f);
        const float inter = iw * ih;
        const float uni   = ((area1 + s_area2[g]) - inter) + EPSF;
        const float iou   = inter / uni;
        const float cw    = fmaxf(pb.z, gx2) - fminf(pb.x, gx1);
        const float ch    = fmaxf(pb.w, gy2) - fminf(pb.y, gy1);
        const float c2    = ((cw * cw) + (ch * ch)) + EPSF;
        const float dx    = (s_gsx[g] - pb.x) - pb.z;   // (g1+g2-p1-p2), left-assoc
        const float dy    = (s_gsy[g] - pb.y) - pb.w;
        const float d2    = ((dx * dx) + (dy * dy)) / 4.0f;
        const float dif   = s_atg[g] - atp;
        const float v     = KPI * (dif * dif);
        const float alpha = v / ((v - iou) + 1.0f);     // f32(1+1e-9) == 1.0f
        const float ciou  = iou - ((d2 / c2) + v * alpha);

        const float cls   = S + s_delta[t * 81 + s_lab[g]];
        const float cst   = (cls + 3.0f * ciou) + (both ? 0.0f : 100000.0f);
        crow[(size_t)g * A_N] = cst;
    }
}

// ---------------------------------------------------------------------------
// Kernel 2: top-10 smallest (value, index) per (b,g) row of 8400
// block = 256 threads, grid = BS*G blocks
// ---------------------------------------------------------------------------
__global__ __launch_bounds__(256)
void k_topk(const float* __restrict__ cost, int* __restrict__ topk)
{
    __shared__ float sv[256 * TK];
    __shared__ int   si[256 * TK];
    __shared__ float s_rv[4];
    __shared__ int   s_ra[4];
    __shared__ int   s_win;

    const int bg = blockIdx.x;
    const int t  = threadIdx.x;
    const float* row = cost + (size_t)bg * A_N;

    const float FINF = __builtin_inff();
    float v[TK]; int id[TK];
    #pragma unroll
    for (int j = 0; j < TK; ++j) { v[j] = FINF; id[j] = 0x7FFFFFFF; }

    for (int a = t; a < A_N; a += 256) {
        const float c = row[a];
        if (lexless(c, a, v[TK - 1], id[TK - 1])) {
            v[TK - 1] = c; id[TK - 1] = a;
            #pragma unroll
            for (int j = TK - 2; j >= 0; --j) {
                const bool sw = lexless(v[j + 1], id[j + 1], v[j], id[j]);
                const float tv = v[j]; const int ti = id[j];
                v[j]      = sw ? v[j + 1] : v[j];
                id[j]     = sw ? id[j + 1] : id[j];
                v[j + 1]  = sw ? tv : v[j + 1];
                id[j + 1] = sw ? ti : id[j + 1];
            }
        }
    }
    #pragma unroll
    for (int j = 0; j < TK; ++j) { sv[t * TK + j] = v[j]; si[t * TK + j] = id[j]; }
    __syncthreads();

    for (int r = 0; r < TK; ++r) {
        float bv = FINF; int ba = 0x7FFFFFFF;
        for (int k = t; k < 256 * TK; k += 256) {
            const float vv = sv[k]; const int ii = si[k];
            if (lexless(vv, ii, bv, ba)) { bv = vv; ba = ii; }
        }
        #pragma unroll
        for (int off = 32; off > 0; off >>= 1) {
            const float ov = __shfl_down(bv, off, 64);
            const int   oa = __shfl_down(ba, off, 64);
            if (lexless(ov, oa, bv, ba)) { bv = ov; ba = oa; }
        }
        if ((t & 63) == 0) { s_rv[t >> 6] = bv; s_ra[t >> 6] = ba; }
        __syncthreads();
        if (t == 0) {
            bv = s_rv[0]; ba = s_ra[0];
            #pragma unroll
            for (int w = 1; w < 4; ++w)
                if (lexless(s_rv[w], s_ra[w], bv, ba)) { bv = s_rv[w]; ba = s_ra[w]; }
            topk[bg * TK + r] = ba;
            s_win = ba;
        }
        __syncthreads();
        const int win = s_win;
        for (int k = t; k < 256 * TK; k += 256)
            if (si[k] == win) { sv[k] = FINF; si[k] = 0x7FFFFFFF; }
        __syncthreads();
    }
}

// ---------------------------------------------------------------------------
// Kernel 3: overlap / argmin-pick / final mask  ->  final[b][g][a] as 0/1 float
// block = 256 threads over 'a', grid = (ceil(A/256), BS)
// ---------------------------------------------------------------------------
__global__ __launch_bounds__(256)
void k_final(const float* __restrict__ cost,
             const int*   __restrict__ topk,
             const unsigned char* __restrict__ mask_gt,  // [BS][G] bool (1 byte)
             float* __restrict__ final_out)              // [BS][G][A]
{
    __shared__ int s_top[G_N * TK];
    __shared__ int s_mask[G_N];

    const int t = threadIdx.x;
    const int b = blockIdx.y;
    const int a = blockIdx.x * 256 + t;

    for (int k = t; k < G_N * TK; k += 256) s_top[k] = topk[b * G_N * TK + k];
    if (t < G_N) s_mask[t] = (int)mask_gt[b * G_N + t];
    __syncthreads();
    if (a >= A_N) return;

    unsigned long long member = 0ull;
    int cnt = 0;
    float best = __builtin_inff();
    int bestg = 0;
    for (int g = 0; g < G_N; ++g) {
        bool m = false;
        if (s_mask[g]) {
            #pragma unroll
            for (int j = 0; j < TK; ++j) m = m || (s_top[g * TK + j] == a);
        }
        if (m) {
            member |= (1ull << g);
            ++cnt;
            const float c = cost[((size_t)b * G_N + g) * A_N + a];
            if (c < best) { best = c; bestg = g; }   // strict <: first-min like argmin
        }
    }
    const bool ovl = cnt > 1;
    float* frow = final_out + (size_t)b * G_N * A_N + a;
    for (int g = 0; g < G_N; ++g) {
        const bool f = ovl ? (g == bestg) : (((member >> g) & 1ull) != 0ull);
        frow[(size_t)g * A_N] = f ? 1.0f : 0.0f;
    }
}

// ---------------------------------------------------------------------------
extern "C" void kernel_launch(void* const* d_in, const int* in_sizes, int n_in,
                              void* d_out, int out_size, void* d_ws, size_t ws_size,
                              hipStream_t stream)
{
    const float* pred_boxes  = (const float*)d_in[0];
    const float* gt_boxes    = (const float*)d_in[1];
    const unsigned char* mask_gt = (const unsigned char*)d_in[2];
    const float* pred_scores = (const float*)d_in[3];
    const int*   gt_labels   = (const int*)d_in[4];

    float* out_final = (float*)d_out;                       // chunk 0: final (bool as f32)
    float* out_cost  = out_final + (size_t)BS * G_N * A_N;  // chunk 1: cost
    int*   topk_ws   = (int*)d_ws;                          // BS*G*TK ints = 80 KiB

    k_cost <<<dim3((A_N + 63) / 64, BS), 64, 0, stream>>>(
        pred_boxes, gt_boxes, pred_scores, gt_labels, out_cost);
    k_topk <<<dim3(BS * G_N), 256, 0, stream>>>(out_cost, topk_ws);
    k_final<<<dim3((A_N + 255) / 256, BS), 256, 0, stream>>>(
        out_cost, topk_ws, mask_gt, out_final);
}

// Round 2
// 437.294 us; speedup vs baseline: 1.1250x; 1.1250x over previous
//
#include <hip/hip_runtime.h>
#include <math.h>

#pragma clang fp contract(off)

#define BS   32
#define A_N  8400
#define G_N  64
#define NC_N 80
#define TK   10

static __device__ __forceinline__ bool lexless(float v1, int i1, float v2, int i2) {
    return (v1 < v2) || (v1 == v2 && i1 < i2);
}

// ---------------------------------------------------------------------------
// Kernel 1: fused cls-cost + CIoU + gating  ->  cost[b][g][a]
// block = 256 threads (4 waves), each thread owns one anchor 'a'
// grid  = (ceil(A/256), BS)
// LDS ~3.6 KB (no per-class delta store: g-loop runs in label-sorted order,
// delta_c kept in one register, recomputed on class change — uniform branch).
// ---------------------------------------------------------------------------
__global__ __launch_bounds__(256)
void k_cost(const float* __restrict__ pred_boxes,   // [BS][A][4]
            const float* __restrict__ gt_boxes,     // [BS][G][4]
            const float* __restrict__ pred_scores,  // [BS][A][NC]
            const int*   __restrict__ gt_labels,    // [BS][G]
            float* __restrict__ cost)               // [BS][G][A]
{
    __shared__ float s_gx1[G_N], s_gy1[G_N], s_gx2[G_N], s_gy2[G_N];
    __shared__ float s_gsx[G_N], s_gsy[G_N];
    __shared__ float s_glx[G_N], s_gly[G_N], s_ghx[G_N], s_ghy[G_N];
    __shared__ float s_area2[G_N], s_atg[G_N];
    __shared__ int   s_lab[G_N];
    __shared__ int   s_ord[G_N];     // gt indices sorted by (label, gt_idx)

    const float EPSF = 1e-9f;
    const int t = threadIdx.x;
    const int b = blockIdx.y;
    const int a = blockIdx.x * 256 + t;

    // --- per-gt preload (threads 0..63 each own one gt)
    if (t < G_N) {
        const float4 gb = ((const float4*)gt_boxes)[b * G_N + t];
        const float gx1 = gb.x, gy1 = gb.y, gx2 = gb.z, gy2 = gb.w;
        s_gx1[t] = gx1; s_gy1[t] = gy1; s_gx2[t] = gx2; s_gy2[t] = gy2;
        const float sx = gx1 + gx2, sy = gy1 + gy2;
        s_gsx[t] = sx; s_gsy[t] = sy;
        const float cx = sx / 2.0f, cy = sy / 2.0f;
        s_glx[t] = cx - 2.5f; s_ghx[t] = cx + 2.5f;
        s_gly[t] = cy - 2.5f; s_ghy[t] = cy + 2.5f;
        const float w2 = gx2 - gx1;
        const float h2 = (gy2 - gy1) + EPSF;
        s_area2[t] = w2 * h2;
        s_atg[t]   = atanf(w2 / h2);
        s_lab[t]   = gt_labels[b * G_N + t];
    }
    __syncthreads();
    // --- rank-sort gts by (label, idx): unique ranks 0..63
    if (t < G_N) {
        const int myl = s_lab[t];
        int rank = 0;
        for (int j = 0; j < G_N; ++j) {
            const int lj = s_lab[j];
            rank += (lj < myl) || (lj == myl && j < t);
        }
        s_ord[rank] = t;
    }
    __syncthreads();
    if (a >= A_N) return;

    // --- per-anchor class term S (sequential order c=0..79, float4 loads)
    const float* prow = pred_scores + ((size_t)b * A_N + a) * NC_N;
    const float LO = 1e-7f;
    const float HI = (float)(1.0 - 1e-7);
    float S = 0.0f;
    {
        const float4* prow4 = (const float4*)prow;
        #pragma unroll
        for (int c4 = 0; c4 < NC_N / 4; ++c4) {
            const float4 pv = prow4[c4];
            float p;
            p = fminf(fmaxf(pv.x, LO), HI); S += log1pf(-p);
            p = fminf(fmaxf(pv.y, LO), HI); S += log1pf(-p);
            p = fminf(fmaxf(pv.z, LO), HI); S += log1pf(-p);
            p = fminf(fmaxf(pv.w, LO), HI); S += log1pf(-p);
        }
        S = -S;
    }

    const float4 pb = ((const float4*)pred_boxes)[(size_t)b * A_N + a];
    const float pcx  = (pb.x + pb.z) / 2.0f;
    const float pcy  = (pb.y + pb.w) / 2.0f;
    const float w1   = pb.z - pb.x;
    const float h1   = (pb.w - pb.y) + EPSF;
    const float area1 = w1 * h1;
    const float atp  = atanf(w1 / h1);
    const float KPI  = (float)(4.0 / (M_PI * M_PI));

    float* crow = cost + (size_t)b * G_N * A_N + a;
    int   cur_c  = -1;
    float delta_c = 0.0f;
    for (int k = 0; k < G_N; ++k) {
        const int g = s_ord[k];           // uniform across block
        const int c = s_lab[g];           // ascending; uniform
        if (c != cur_c) {                 // uniform branch
            float p = prow[c];            // L1 hit (row just read)
            p = fminf(fmaxf(p, LO), HI);
            delta_c = log1pf(-p) - logf(p);   // == -(logp - log1mp) bit-exact
            cur_c = c;
        }

        const float gx1 = s_gx1[g], gy1 = s_gy1[g], gx2 = s_gx2[g], gy2 = s_gy2[g];
        const bool inb  = (pcx > gx1) && (pcy > gy1) && (gx2 > pcx) && (gy2 > pcy);
        const bool inc  = (pcx > s_glx[g]) && (pcy > s_gly[g]) &&
                          (s_ghx[g] > pcx) && (s_ghy[g] > pcy);
        const bool both = inb && inc;

        const float iw    = fmaxf(fminf(pb.z, gx2) - fmaxf(pb.x, gx1), 0.0f);
        const float ih    = fmaxf(fminf(pb.w, gy2) - fmaxf(pb.y, gy1), 0.0f);
        const float inter = iw * ih;
        const float uni   = ((area1 + s_area2[g]) - inter) + EPSF;
        const float iou   = inter / uni;
        const float cw    = fmaxf(pb.z, gx2) - fminf(pb.x, gx1);
        const float ch    = fmaxf(pb.w, gy2) - fminf(pb.y, gy1);
        const float c2    = ((cw * cw) + (ch * ch)) + EPSF;
        const float dx    = (s_gsx[g] - pb.x) - pb.z;
        const float dy    = (s_gsy[g] - pb.y) - pb.w;
        const float d2    = ((dx * dx) + (dy * dy)) / 4.0f;
        const float dif   = s_atg[g] - atp;
        const float v     = KPI * (dif * dif);
        const float alpha = v / ((v - iou) + 1.0f);
        const float ciou  = iou - ((d2 / c2) + v * alpha);

        const float cls   = S + delta_c;
        const float cst   = (cls + 3.0f * ciou) + (both ? 0.0f : 100000.0f);
        crow[(size_t)g * A_N] = cst;
    }
}

// ---------------------------------------------------------------------------
// Kernel 2: top-10 smallest (value, index) per (b,g) row of 8400
// block = 256 threads, grid = BS*G blocks
// ---------------------------------------------------------------------------
__global__ __launch_bounds__(256)
void k_topk(const float* __restrict__ cost, int* __restrict__ topk)
{
    __shared__ float sv[256 * TK];
    __shared__ int   si[256 * TK];
    __shared__ float s_rv[4];
    __shared__ int   s_ra[4];
    __shared__ int   s_win;

    const int bg = blockIdx.x;
    const int t  = threadIdx.x;
    const float* row = cost + (size_t)bg * A_N;

    const float FINF = __builtin_inff();
    float v[TK]; int id[TK];
    #pragma unroll
    for (int j = 0; j < TK; ++j) { v[j] = FINF; id[j] = 0x7FFFFFFF; }

    auto consider = [&](float c, int a) {
        if (lexless(c, a, v[TK - 1], id[TK - 1])) {
            v[TK - 1] = c; id[TK - 1] = a;
            #pragma unroll
            for (int j = TK - 2; j >= 0; --j) {
                const bool sw = lexless(v[j + 1], id[j + 1], v[j], id[j]);
                const float tv = v[j]; const int ti = id[j];
                v[j]      = sw ? v[j + 1] : v[j];
                id[j]     = sw ? id[j + 1] : id[j];
                v[j + 1]  = sw ? tv : v[j + 1];
                id[j + 1] = sw ? ti : id[j + 1];
            }
        }
    };

    const float4* row4 = (const float4*)row;
    for (int i = t; i < A_N / 4; i += 256) {   // 8400/4 = 2100
        const float4 c4 = row4[i];
        const int base = i * 4;
        consider(c4.x, base);
        consider(c4.y, base + 1);
        consider(c4.z, base + 2);
        consider(c4.w, base + 3);
    }
    #pragma unroll
    for (int j = 0; j < TK; ++j) { sv[t * TK + j] = v[j]; si[t * TK + j] = id[j]; }
    __syncthreads();

    for (int r = 0; r < TK; ++r) {
        float bv = FINF; int ba = 0x7FFFFFFF;
        for (int k = t; k < 256 * TK; k += 256) {
            const float vv = sv[k]; const int ii = si[k];
            if (lexless(vv, ii, bv, ba)) { bv = vv; ba = ii; }
        }
        #pragma unroll
        for (int off = 32; off > 0; off >>= 1) {
            const float ov = __shfl_down(bv, off, 64);
            const int   oa = __shfl_down(ba, off, 64);
            if (lexless(ov, oa, bv, ba)) { bv = ov; ba = oa; }
        }
        if ((t & 63) == 0) { s_rv[t >> 6] = bv; s_ra[t >> 6] = ba; }
        __syncthreads();
        if (t == 0) {
            bv = s_rv[0]; ba = s_ra[0];
            #pragma unroll
            for (int w = 1; w < 4; ++w)
                if (lexless(s_rv[w], s_ra[w], bv, ba)) { bv = s_rv[w]; ba = s_ra[w]; }
            topk[bg * TK + r] = ba;
            s_win = ba;
        }
        __syncthreads();
        const int win = s_win;
        for (int k = t; k < 256 * TK; k += 256)
            if (si[k] == win) { sv[k] = FINF; si[k] = 0x7FFFFFFF; }
        __syncthreads();
    }
}

// ---------------------------------------------------------------------------
// Kernel 3: overlap / argmin-pick / final mask  ->  final[b][g][a] as 0/1 float
// block = 256 threads over 'a', grid = (ceil(A/256), BS)
// ---------------------------------------------------------------------------
__global__ __launch_bounds__(256)
void k_final(const float* __restrict__ cost,
             const int*   __restrict__ topk,
             const unsigned char* __restrict__ mask_gt,  // [BS][G] bool (1 byte)
             float* __restrict__ final_out)              // [BS][G][A]
{
    __shared__ int s_top[G_N * TK];
    __shared__ int s_mask[G_N];

    const int t = threadIdx.x;
    const int b = blockIdx.y;
    const int a = blockIdx.x * 256 + t;

    for (int k = t; k < G_N * TK; k += 256) s_top[k] = topk[b * G_N * TK + k];
    if (t < G_N) s_mask[t] = (int)mask_gt[b * G_N + t];
    __syncthreads();
    if (a >= A_N) return;

    unsigned long long member = 0ull;
    int cnt = 0;
    float best = __builtin_inff();
    int bestg = 0;
    for (int g = 0; g < G_N; ++g) {
        bool m = false;
        if (s_mask[g]) {
            #pragma unroll
            for (int j = 0; j < TK; ++j) m = m || (s_top[g * TK + j] == a);
        }
        if (m) {
            member |= (1ull << g);
            ++cnt;
            const float c = cost[((size_t)b * G_N + g) * A_N + a];
            if (c < best) { best = c; bestg = g; }   // strict <: first-min like argmin
        }
    }
    const bool ovl = cnt > 1;
    float* frow = final_out + (size_t)b * G_N * A_N + a;
    for (int g = 0; g < G_N; ++g) {
        const bool f = ovl ? (g == bestg) : (((member >> g) & 1ull) != 0ull);
        frow[(size_t)g * A_N] = f ? 1.0f : 0.0f;
    }
}

// ---------------------------------------------------------------------------
extern "C" void kernel_launch(void* const* d_in, const int* in_sizes, int n_in,
                              void* d_out, int out_size, void* d_ws, size_t ws_size,
                              hipStream_t stream)
{
    const float* pred_boxes  = (const float*)d_in[0];
    const float* gt_boxes    = (const float*)d_in[1];
    const unsigned char* mask_gt = (const unsigned char*)d_in[2];
    const float* pred_scores = (const float*)d_in[3];
    const int*   gt_labels   = (const int*)d_in[4];

    float* out_final = (float*)d_out;                       // chunk 0: final (bool as f32)
    float* out_cost  = out_final + (size_t)BS * G_N * A_N;  // chunk 1: cost
    int*   topk_ws   = (int*)d_ws;                          // BS*G*TK ints = 80 KiB

    k_cost <<<dim3((A_N + 255) / 256, BS), 256, 0, stream>>>(
        pred_boxes, gt_boxes, pred_scores, gt_labels, out_cost);
    k_topk <<<dim3(BS * G_N), 256, 0, stream>>>(out_cost, topk_ws);
    k_final<<<dim3((A_N + 255) / 256, BS), 256, 0, stream>>>(
        out_cost, topk_ws, mask_gt, out_final);
}

// Round 3
// 355.192 us; speedup vs baseline: 1.3850x; 1.2311x over previous
//
#include <hip/hip_runtime.h>
#include <math.h>

#define BS   32
#define A_N  8400
#define G_N  64
#define NC_N 80
#define TK   10
#define DROWS 44   // LDS delta rows; ranks >= DROWS use fallback reload (rare)

static __device__ __forceinline__ bool lexless(float v1, int i1, float v2, int i2) {
    return (v1 < v2) || (v1 == v2 && i1 < i2);
}
static __device__ __forceinline__ float fdiv(float n, float d) {
    return n * __builtin_amdgcn_rcpf(d);   // v_rcp_f32: ~1 ulp, fine vs selection gaps
}

// ---------------------------------------------------------------------------
// Kernel 1: fused cls-cost + CIoU + gating  ->  cost[b][g][a]
// 256 threads, thread = one anchor. S via grouped-product logs (10 logf, no
// log1pf). Per-distinct-class delta captured to LDS during the score stream
// (no scattered global re-reads). g-loop in label-sorted order.
// ---------------------------------------------------------------------------
__global__ __launch_bounds__(256)
void k_cost(const float* __restrict__ pred_boxes,   // [BS][A][4]
            const float* __restrict__ gt_boxes,     // [BS][G][4]
            const float* __restrict__ pred_scores,  // [BS][A][NC]
            const int*   __restrict__ gt_labels,    // [BS][G]
            float* __restrict__ cost)               // [BS][G][A]
{
    __shared__ float s_gx1[G_N], s_gy1[G_N], s_gx2[G_N], s_gy2[G_N];
    __shared__ float s_gsx[G_N], s_gsy[G_N];
    __shared__ float s_glx[G_N], s_gly[G_N], s_ghx[G_N], s_ghy[G_N];
    __shared__ float s_area2[G_N], s_atg[G_N];
    __shared__ int   s_lab[G_N];
    __shared__ int   s_ord[G_N];      // gt indices sorted by (label, gt_idx)
    __shared__ int   s_pres[NC_N];    // class present?
    __shared__ int   s_rank[NC_N];    // class -> dense rank among present, or -1
    __shared__ float s_delta[DROWS * 256];   // [rank][tid] per-thread delta

    const float EPSF = 1e-9f;
    const int t = threadIdx.x;
    const int b = blockIdx.y;
    const int a = blockIdx.x * 256 + t;

    if (t < G_N) {
        const float4 gb = ((const float4*)gt_boxes)[b * G_N + t];
        const float gx1 = gb.x, gy1 = gb.y, gx2 = gb.z, gy2 = gb.w;
        s_gx1[t] = gx1; s_gy1[t] = gy1; s_gx2[t] = gx2; s_gy2[t] = gy2;
        const float sx = gx1 + gx2, sy = gy1 + gy2;
        s_gsx[t] = sx; s_gsy[t] = sy;
        const float cx = sx / 2.0f, cy = sy / 2.0f;
        s_glx[t] = cx - 2.5f; s_ghx[t] = cx + 2.5f;
        s_gly[t] = cy - 2.5f; s_ghy[t] = cy + 2.5f;
        const float w2 = gx2 - gx1;
        const float h2 = (gy2 - gy1) + EPSF;
        s_area2[t] = w2 * h2;
        s_atg[t]   = atanf(w2 / h2);
        s_lab[t]   = gt_labels[b * G_N + t];
    }
    __syncthreads();
    if (t < NC_N) {
        int pr = 0;
        for (int j = 0; j < G_N; ++j) pr |= (s_lab[j] == t);
        s_pres[t] = pr;
    }
    if (t < G_N) {   // rank-sort gts by (label, idx): unique ranks
        const int myl = s_lab[t];
        int rank = 0;
        for (int j = 0; j < G_N; ++j) {
            const int lj = s_lab[j];
            rank += (lj < myl) || (lj == myl && j < t);
        }
        s_ord[rank] = t;
    }
    __syncthreads();
    if (t < NC_N) {
        int r = 0;
        for (int c = 0; c < t; ++c) r += s_pres[c];
        s_rank[t] = s_pres[t] ? r : -1;
    }
    __syncthreads();
    if (a >= A_N) return;

    // --- streamed score pass: grouped-product S + delta capture
    const float* prow = pred_scores + ((size_t)b * A_N + a) * NC_N;
    const float LO = 1e-7f;
    const float HI = (float)(1.0 - 1e-7);
    float prod = 1.0f, Sacc = 0.0f;
    {
        const float4* p4 = (const float4*)prow;
        for (int c4 = 0; c4 < NC_N / 4; ++c4) {
            const float4 pv = p4[c4];
            const float ps[4] = {pv.x, pv.y, pv.z, pv.w};
            #pragma unroll
            for (int j = 0; j < 4; ++j) {
                const float pc = fminf(fmaxf(ps[j], LO), HI);
                const float q  = 1.0f - pc;
                prod *= q;
                const int r = s_rank[c4 * 4 + j];
                if (r >= 0 && r < DROWS)
                    s_delta[r * 256 + t] = logf(q * __builtin_amdgcn_rcpf(pc));
            }
            if (c4 & 1) { Sacc += logf(prod); prod = 1.0f; }  // 8-class groups
        }
    }
    const float S = -Sacc;

    const float4 pb = ((const float4*)pred_boxes)[(size_t)b * A_N + a];
    const float pcx  = (pb.x + pb.z) / 2.0f;
    const float pcy  = (pb.y + pb.w) / 2.0f;
    const float w1   = pb.z - pb.x;
    const float h1   = (pb.w - pb.y) + EPSF;
    const float area1 = w1 * h1;
    const float atp  = atanf(w1 / h1);
    const float KPI  = (float)(4.0 / (M_PI * M_PI));

    float* crow = cost + (size_t)b * G_N * A_N + a;
    int   cur_c = -1, krank = -1;
    float delta_c = 0.0f;
    for (int k = 0; k < G_N; ++k) {
        const int g = s_ord[k];           // uniform across block
        const int c = s_lab[g];           // ascending; uniform
        if (c != cur_c) {
            ++krank;
            if (krank < DROWS) {
                delta_c = s_delta[krank * 256 + t];
            } else {                      // rare overflow: reload + recompute
                const float pc = fminf(fmaxf(prow[c], LO), HI);
                delta_c = logf((1.0f - pc) * __builtin_amdgcn_rcpf(pc));
            }
            cur_c = c;
        }

        const float gx1 = s_gx1[g], gy1 = s_gy1[g], gx2 = s_gx2[g], gy2 = s_gy2[g];
        const bool inb  = (pcx > gx1) && (pcy > gy1) && (gx2 > pcx) && (gy2 > pcy);
        const bool inc  = (pcx > s_glx[g]) && (pcy > s_gly[g]) &&
                          (s_ghx[g] > pcx) && (s_ghy[g] > pcy);
        const bool both = inb && inc;

        const float iw    = fmaxf(fminf(pb.z, gx2) - fmaxf(pb.x, gx1), 0.0f);
        const float ih    = fmaxf(fminf(pb.w, gy2) - fmaxf(pb.y, gy1), 0.0f);
        const float inter = iw * ih;
        const float uni   = ((area1 + s_area2[g]) - inter) + EPSF;
        const float iou   = fdiv(inter, uni);
        const float cw    = fmaxf(pb.z, gx2) - fminf(pb.x, gx1);
        const float ch    = fmaxf(pb.w, gy2) - fminf(pb.y, gy1);
        const float c2    = ((cw * cw) + (ch * ch)) + EPSF;
        const float dx    = (s_gsx[g] - pb.x) - pb.z;
        const float dy    = (s_gsy[g] - pb.y) - pb.w;
        const float d2    = ((dx * dx) + (dy * dy)) / 4.0f;
        const float dif   = s_atg[g] - atp;
        const float v     = KPI * (dif * dif);
        const float alpha = fdiv(v, (v - iou) + 1.0f);
        const float ciou  = iou - (fdiv(d2, c2) + v * alpha);

        const float cls   = S + delta_c;
        const float cst   = (cls + 3.0f * ciou) + (both ? 0.0f : 100000.0f);
        crow[(size_t)g * A_N] = cst;
    }
}

// ---------------------------------------------------------------------------
// Kernel 2: top-10 smallest (value, index) per (b,g) row of 8400
// Register-resident sorted lists; shuffle-butterfly k-way merge.
// ---------------------------------------------------------------------------
__global__ __launch_bounds__(256)
void k_topk(const float* __restrict__ cost, int* __restrict__ topk)
{
    __shared__ float s_wv[4][TK];
    __shared__ int   s_wi[4][TK];

    const int bg   = blockIdx.x;
    const int t    = threadIdx.x;
    const int lane = t & 63;
    const int wid  = t >> 6;
    const float* row = cost + (size_t)bg * A_N;
    const float FINF = __builtin_inff();

    float v[TK]; int id[TK];
    #pragma unroll
    for (int j = 0; j < TK; ++j) { v[j] = FINF; id[j] = 0x7FFFFFFF; }

    auto consider = [&](float c, int a) {
        if (lexless(c, a, v[TK - 1], id[TK - 1])) {
            v[TK - 1] = c; id[TK - 1] = a;
            #pragma unroll
            for (int j = TK - 2; j >= 0; --j) {
                const bool sw = lexless(v[j + 1], id[j + 1], v[j], id[j]);
                const float tv = v[j]; const int ti = id[j];
                v[j]      = sw ? v[j + 1] : v[j];
                id[j]     = sw ? id[j + 1] : id[j];
                v[j + 1]  = sw ? tv : v[j + 1];
                id[j + 1] = sw ? ti : id[j + 1];
            }
        }
    };

    const float4* row4 = (const float4*)row;
    for (int i = t; i < A_N / 4; i += 256) {
        const float4 c4 = row4[i];
        const int base = i * 4;
        consider(c4.x, base);
        consider(c4.y, base + 1);
        consider(c4.z, base + 2);
        consider(c4.w, base + 3);
    }

    // --- stage 1: wave-level merge, 10 rounds of 64-lane argmin + winner pop
    #pragma unroll
    for (int r = 0; r < TK; ++r) {
        float bv = v[0]; int ba = id[0];
        #pragma unroll
        for (int off = 1; off < 64; off <<= 1) {
            const float ov = __shfl_xor(bv, off, 64);
            const int   oa = __shfl_xor(ba, off, 64);
            if (lexless(ov, oa, bv, ba)) { bv = ov; ba = oa; }
        }
        if (lane == 0) { s_wv[wid][r] = bv; s_wi[wid][r] = ba; }
        if (id[0] == ba) {                     // unique winner pops its list
            #pragma unroll
            for (int j = 0; j < TK - 1; ++j) { v[j] = v[j + 1]; id[j] = id[j + 1]; }
            v[TK - 1] = FINF; id[TK - 1] = 0x7FFFFFFF;
        }
    }
    __syncthreads();

    // --- stage 2: wave 0 merges 4 sorted 10-lists (one candidate per lane)
    if (wid == 0) {
        float cv = FINF; int ci = 0x7FFFFFFF;
        if (lane < 4 * TK) { cv = s_wv[lane / TK][lane % TK]; ci = s_wi[lane / TK][lane % TK]; }
        #pragma unroll
        for (int r = 0; r < TK; ++r) {
            float bv = cv; int ba = ci;
            #pragma unroll
            for (int off = 1; off < 64; off <<= 1) {
                const float ov = __shfl_xor(bv, off, 64);
                const int   oa = __shfl_xor(ba, off, 64);
                if (lexless(ov, oa, bv, ba)) { bv = ov; ba = oa; }
            }
            if (lane == 0) topk[bg * TK + r] = ba;
            if (ci == ba) { cv = FINF; ci = 0x7FFFFFFF; }
        }
    }
}

// ---------------------------------------------------------------------------
// Kernel 3: overlap / argmin-pick / final mask  ->  final[b][g][a] as 0/1 float
// ---------------------------------------------------------------------------
__global__ __launch_bounds__(256)
void k_final(const float* __restrict__ cost,
             const int*   __restrict__ topk,
             const unsigned char* __restrict__ mask_gt,
             float* __restrict__ final_out)
{
    __shared__ int s_top[G_N * TK];
    __shared__ int s_mask[G_N];

    const int t = threadIdx.x;
    const int b = blockIdx.y;
    const int a = blockIdx.x * 256 + t;

    for (int k = t; k < G_N * TK; k += 256) s_top[k] = topk[b * G_N * TK + k];
    if (t < G_N) s_mask[t] = (int)mask_gt[b * G_N + t];
    __syncthreads();
    if (a >= A_N) return;

    unsigned long long member = 0ull;
    int cnt = 0;
    float best = __builtin_inff();
    int bestg = 0;
    for (int g = 0; g < G_N; ++g) {
        bool m = false;
        if (s_mask[g]) {
            #pragma unroll
            for (int j = 0; j < TK; ++j) m = m || (s_top[g * TK + j] == a);
        }
        if (m) {
            member |= (1ull << g);
            ++cnt;
            const float c = cost[((size_t)b * G_N + g) * A_N + a];
            if (c < best) { best = c; bestg = g; }
        }
    }
    const bool ovl = cnt > 1;
    float* frow = final_out + (size_t)b * G_N * A_N + a;
    for (int g = 0; g < G_N; ++g) {
        const bool f = ovl ? (g == bestg) : (((member >> g) & 1ull) != 0ull);
        frow[(size_t)g * A_N] = f ? 1.0f : 0.0f;
    }
}

// ---------------------------------------------------------------------------
extern "C" void kernel_launch(void* const* d_in, const int* in_sizes, int n_in,
                              void* d_out, int out_size, void* d_ws, size_t ws_size,
                              hipStream_t stream)
{
    const float* pred_boxes  = (const float*)d_in[0];
    const float* gt_boxes    = (const float*)d_in[1];
    const unsigned char* mask_gt = (const unsigned char*)d_in[2];
    const float* pred_scores = (const float*)d_in[3];
    const int*   gt_labels   = (const int*)d_in[4];

    float* out_final = (float*)d_out;
    float* out_cost  = out_final + (size_t)BS * G_N * A_N;
    int*   topk_ws   = (int*)d_ws;

    k_cost <<<dim3((A_N + 255) / 256, BS), 256, 0, stream>>>(
        pred_boxes, gt_boxes, pred_scores, gt_labels, out_cost);
    k_topk <<<dim3(BS * G_N), 256, 0, stream>>>(out_cost, topk_ws);
    k_final<<<dim3((A_N + 255) / 256, BS), 256, 0, stream>>>(
        out_cost, topk_ws, mask_gt, out_final);
}